// Round 2
// baseline (502.232 us; speedup 1.0000x reference)
//
#include <hip/hip_runtime.h>
#include <math.h>

#define NCLS 19
#define HW   (512*1024)          // 524288
#define CHW  (NCLS*HW)
#define TPIX (2*HW)              // 1048576
#define NB   512                 // coarse bins
#define NPART 32                 // partial histogram copies (blocks of N2)
#define CAND_MAX 4096
#define SUBB 1024                // refinement sub-bins per coarse bin
#define SCAP 256                 // refinement candidate cap (per class)

// ---- workspace layout (bytes) ----
// u16 partials: NPART*NCLS*NB*2 = 32*19*512*2 = 622592 (same slot as before)
#define WS_PART   0
#define WS_CANDC  622592                     // NCLS*4 candidate counters
#define WS_ACCUM  622720                     // [0]=sum_loss f32, [1]=cnt_mask u32, [2]=cnt_solid u32
#define WS_DONE   622784                     // [0]=N2 ticket, [1]=N3 ticket, [2]=N4 ticket
#define WS_SEL    622848                     // NCLS * {int bin, int rank}
#define WS_NEWTH  623360                     // NCLS*4
#define WS_CONF   623616                     // TPIX*4
#define WS_LOSS   4817920                    // TPIX*4
#define WS_LABEL  9012224                    // TPIX*1
#define WS_CAND   10060800                   // NCLS*CAND_MAX*4 -> end 10372096

// ---------------- N1: block-cooperative 16B DMA + per-pixel softmax stats ----------------
// R2 change: 256-px tile per block, staged with 38 x 1KB global_load_lds width=16
// (4x fewer DMA instructions than the 4B/lane version). Block 0 also zeroes the
// control words (replaces the hipMemsetAsync node).
#define TILE 256
__global__ __launch_bounds__(256)
void k1_pixel(const float* __restrict__ lb_t, const float* __restrict__ la_t,
              float* __restrict__ conf_o, float* __restrict__ loss_o,
              unsigned char* __restrict__ label_o,
              unsigned int* __restrict__ cand_cnt,
              unsigned int* __restrict__ accum_u,
              unsigned int* __restrict__ done)
{
    __shared__ float smem[2 * NCLS * TILE];            // 38912 B -> 4 blocks/CU
    const int tid = threadIdx.x;
    if (blockIdx.x == 0) {                             // zero control area (consumed in N2+)
        if (tid < NCLS)            cand_cnt[tid] = 0u;
        else if (tid < NCLS + 3)   accum_u[tid - NCLS] = 0u;
        else if (tid < NCLS + 6)   done[tid - NCLS - 3] = 0u;
    }
    const int wave = tid >> 6, lane = tid & 63;
    const int tb  = blockIdx.x * TILE;                 // tile never straddles N (HW%256==0)
    const int n   = tb >> 19;
    const int rem = tb & (HW - 1);
    const float* lb = lb_t + (size_t)n * CHW + rem;
    const float* la = la_t + (size_t)n * CHW + rem;

    // 38 channel-rows of 256 px = 1 KB each; wave w stages rows w, w+4, ...
    // lane l loads 16B at row+4*l floats -> LDS base+16*l (linear, matches HW rule)
#pragma unroll
    for (int i = 0; i < 10; ++i) {
        int r = wave + 4 * i;
        if (r < 2 * NCLS) {
            const float* src = (r < NCLS) ? (lb + (size_t)r * HW)
                                          : (la + (size_t)(r - NCLS) * HW);
            __builtin_amdgcn_global_load_lds(
                (__attribute__((address_space(1))) void*)(src + (lane << 2)),
                (__attribute__((address_space(3))) void*)(smem + r * TILE),
                16, 0, 0);
        }
    }
    asm volatile("s_waitcnt vmcnt(0)" ::: "memory");
    __syncthreads();

    const int pix = tb + tid;                          // thread t owns px t of the tile
    float mb, zb, dot, a_lab, ma, za; int lab;
    {
        float bb = smem[tid];
        float aa = smem[NCLS * TILE + tid];
        mb = bb; zb = 1.0f; dot = aa; lab = 0; a_lab = aa; ma = aa; za = 1.0f;
    }
#pragma unroll
    for (int c = 1; c < NCLS; ++c) {
        float b = smem[c * TILE + tid];
        float a = smem[(NCLS + c) * TILE + tid];
        float mn = fmaxf(mb, b);
        float eo = __expf(mb - mn);
        float en = __expf(b - mn);
        zb  = zb * eo + en;
        dot = dot * eo + en * a;
        bool upd = b > mb;                  // first-max-wins (strict >)
        lab   = upd ? c : lab;
        a_lab = upd ? a : a_lab;
        mb = mn;
        float mna = fmaxf(ma, a);
        za = za * __expf(ma - mna) + __expf(a - mna);
        ma = mna;
    }

    float cf = 1.0f / zb;
    float pa_lab = __expf(a_lab - ma) / za;
    float ls = (1.0f - pa_lab) * (ma + __logf(za) - dot / zb);

    conf_o[pix]  = cf;
    loss_o[pix]  = ls;
    label_o[pix] = (unsigned char)lab;
}

// ---------------- N2: partial hists + last-block reduce & per-class selection ----------------
__global__ __launch_bounds__(256)
void k2_hist_select(const float4* __restrict__ conf, const uchar4* __restrict__ label,
                    unsigned short* __restrict__ part, const float* __restrict__ cls_thresh,
                    int* __restrict__ sel, unsigned int* __restrict__ cand_cnt,
                    float* __restrict__ cand, unsigned int* __restrict__ done)
{
    __shared__ unsigned int lh[NCLS * NB];             // 38912 B
    __shared__ int s_last;
    const int t = threadIdx.x;
    for (int w = t; w < NCLS * NB; w += 256) lh[w] = 0u;
    __syncthreads();

    const int per4  = TPIX / 4 / NPART;                // 8192 float4 per block
    const int base4 = blockIdx.x * per4;
    for (int i = 0; i < per4 / 256; ++i) {             // 32 iterations
        int g = base4 + i * 256 + t;
        float4 c4 = conf[g];
        uchar4 l4 = label[g];
        float cf[4] = {c4.x, c4.y, c4.z, c4.w};
        int   lb[4] = {l4.x, l4.y, l4.z, l4.w};
#pragma unroll
        for (int k = 0; k < 4; ++k) {
            int bin = (int)(cf[k] * (float)NB);
            bin = bin < (NB - 1) ? bin : (NB - 1);
            atomicAdd(&lh[lb[k] * NB + bin], 1u);
        }
    }
    __syncthreads();

    unsigned short* dst = part + blockIdx.x * (NCLS * NB);
    for (int w = t; w < NCLS * NB; w += 256) dst[w] = (unsigned short)lh[w];  // <=32768 fits u16

    __threadfence();                                   // release partials
    if (t == 0) s_last = (atomicAdd(&done[0], 1u) == (unsigned)(NPART - 1)) ? 1 : 0;
    __syncthreads();
    if (!s_last) return;
    __threadfence();                                   // acquire: invalidate stale L2 lines

    // reduce 32 u16 partials -> full hist in LDS
    for (int w = t; w < NCLS * NB; w += 256) {
        unsigned s = 0;
        for (int b = 0; b < NPART; ++b) s += part[b * (NCLS * NB) + w];
        lh[w] = s;
    }
    __syncthreads();

    // per-wave selection: wave w handles classes w, w+4, ... (no barriers needed)
    const int wave = t >> 6, lane = t & 63;
    for (int c = wave; c < NCLS; c += 4) {
        float thr = cls_thresh[c];
        int thr_bin = (int)(thr * (float)NB); thr_bin = thr_bin < (NB - 1) ? thr_bin : (NB - 1);
        // lane l owns DESCENDING chunk of 8 bins: [NB-8*(l+1), NB-8*l)
        int cb = NB - 8 * (lane + 1);
        unsigned hsum = 0;
        for (int i = 0; i < 8; ++i) {
            unsigned h = lh[c * NB + cb + i];
            if (cb + i == thr_bin) h += 1u;            // extended multiset: append thr
            hsum += h;
        }
        unsigned incl = hsum;                          // inclusive scan over lanes (lane0=highest bins)
        for (int off = 1; off < 64; off <<= 1) {
            unsigned v = __shfl_up(incl, off, 64);
            if (lane >= off) incl += v;
        }
        unsigned total_ext = __shfl(incl, 63, 64);     // count_c + 1
        unsigned cnt = total_ext - 1u;
        int idx = (int)floorf((float)(cnt + 1u) * 0.2f * powf(thr, 8.0f));
        unsigned above = incl - hsum;
        if ((unsigned)idx >= above && (unsigned)idx < above + hsum) {
            unsigned cum = above; int B = thr_bin, r = 0;
            for (int i = 7; i >= 0; --i) {             // walk chunk from highest bin
                int bi = cb + i;
                unsigned h = lh[c * NB + bi];
                if (bi == thr_bin) h += 1u;
                if ((unsigned)idx < cum + h) { B = bi; r = (int)((unsigned)idx - cum); break; }
                cum += h;
            }
            sel[2 * c]     = B;
            sel[2 * c + 1] = r;
            if (B == thr_bin) {                        // appended thr is a candidate
                unsigned pos = atomicAdd(&cand_cnt[c], 1u);
                if (pos < CAND_MAX) cand[c * CAND_MAX + pos] = thr;
            }
        }
    }
}

// ---------------- N3: gather candidates + last-block refined exact selection ----------------
__global__ __launch_bounds__(256)
void k3_gather_thresh(const float4* __restrict__ conf, const uchar4* __restrict__ label,
                      const int* __restrict__ sel, unsigned int* __restrict__ cand_cnt,
                      float* __restrict__ cand, const float* __restrict__ cls_thresh,
                      float* __restrict__ newth, unsigned int* __restrict__ done)
{
    const int t = threadIdx.x;
    {
        int g = blockIdx.x * 256 + t;
        float4 c4 = conf[g];
        uchar4 l4 = label[g];
        float cf[4] = {c4.x, c4.y, c4.z, c4.w};
        int   lb[4] = {l4.x, l4.y, l4.z, l4.w};
#pragma unroll
        for (int i = 0; i < 4; ++i) {
            int bin = (int)(cf[i] * (float)NB);
            bin = bin < (NB - 1) ? bin : (NB - 1);
            if (bin == sel[2 * lb[i]]) {
                unsigned pos = atomicAdd(&cand_cnt[lb[i]], 1u);
                if (pos < CAND_MAX) cand[lb[i] * CAND_MAX + pos] = cf[i];
            }
        }
    }
    __threadfence();
    __shared__ int s_last;
    if (t == 0) s_last = (atomicAdd(&done[1], 1u) == (unsigned)(gridDim.x - 1)) ? 1 : 0;
    __syncthreads();
    if (!s_last) return;
    __threadfence();                                   // acquire

    // per-wave exact rank selection via sub-bin refinement (O(m) typical)
    __shared__ unsigned int subh[4][SUBB];             // 16 KB
    __shared__ float        sbuf[4][SCAP];             // 4 KB
    __shared__ unsigned int scnt[4];
    const int wave = t >> 6, lane = t & 63;
    for (int c = wave; c < NCLS; c += 4) {
        unsigned mc = cand_cnt[c];
        int m = (int)(mc < (unsigned)CAND_MAX ? mc : (unsigned)CAND_MAX);
        int B = sel[2 * c];
        int r = sel[2 * c + 1];
        const float* v = cand + c * CAND_MAX;

        for (int i = lane; i < SUBB; i += 64) subh[wave][i] = 0u;
        if (lane == 0) scnt[wave] = 0u;
        asm volatile("s_waitcnt lgkmcnt(0)" ::: "memory");

        const float scale = (float)NB;
        for (int i = lane; i < m; i += 64) {
            float x = v[i];
            int s = (int)((x * scale - (float)B) * (float)SUBB);
            s = s < 0 ? 0 : (s > SUBB - 1 ? SUBB - 1 : s);
            atomicAdd(&subh[wave][s], 1u);
        }
        asm volatile("s_waitcnt lgkmcnt(0)" ::: "memory");

        // lane l owns DESCENDING chunk of 16 sub-bins
        int cb = SUBB - 16 * (lane + 1);
        unsigned hsum = 0;
        for (int i = 0; i < 16; ++i) hsum += subh[wave][cb + i];
        unsigned incl = hsum;
        for (int off = 1; off < 64; off <<= 1) {
            unsigned q = __shfl_up(incl, off, 64);
            if (lane >= off) incl += q;
        }
        unsigned above = incl - hsum;
        int S = -1; unsigned r2 = 0;
        if ((unsigned)r >= above && (unsigned)r < above + hsum) {
            unsigned cum = above;
            for (int i = 15; i >= 0; --i) {
                unsigned h = subh[wave][cb + i];
                if ((unsigned)r < cum + h) { S = cb + i; r2 = (unsigned)r - cum; break; }
                cum += h;
            }
        }
        unsigned long long bal = __ballot(S >= 0);
        int wl = (int)__ffsll((unsigned long long)bal) - 1;
        S  = __shfl(S, wl, 64);
        r2 = (unsigned)__shfl((int)r2, wl, 64);

        // gather sub-bin members (expected << SCAP)
        for (int i = lane; i < m; i += 64) {
            float x = v[i];
            int s = (int)((x * scale - (float)B) * (float)SUBB);
            s = s < 0 ? 0 : (s > SUBB - 1 ? SUBB - 1 : s);
            if (s == S) {
                unsigned p = atomicAdd(&scnt[wave], 1u);
                if (p < (unsigned)SCAP) sbuf[wave][p] = x;
            }
        }
        asm volatile("s_waitcnt lgkmcnt(0)" ::: "memory");
        unsigned cntS = scnt[wave];

        float res = 0.0f; bool have = false;
        if (cntS <= (unsigned)SCAP) {
            for (int i = lane; i < (int)cntS; i += 64) {
                float x = sbuf[wave][i];
                int gc = 0, e = 0;
                for (int j = 0; j < (int)cntS; ++j) {
                    float y = sbuf[wave][j];
                    gc += (y > x); e += (y == x);
                }
                if (gc <= (int)r2 && (int)r2 < gc + e) { res = x; have = true; }
            }
        } else {
            // safety fallback (dead in practice): exact O(m^2) restricted to sub-bin S
            for (int i = lane; i < m; i += 64) {
                float x = v[i];
                int s = (int)((x * scale - (float)B) * (float)SUBB);
                s = s < 0 ? 0 : (s > SUBB - 1 ? SUBB - 1 : s);
                if (s != S) continue;
                int gc = 0, e = 0;
                for (int j = 0; j < m; ++j) {
                    float y = v[j];
                    int sj = (int)((y * scale - (float)B) * (float)SUBB);
                    sj = sj < 0 ? 0 : (sj > SUBB - 1 ? SUBB - 1 : sj);
                    if (sj != S) continue;
                    gc += (y > x); e += (y == x);
                }
                if (gc <= (int)r2 && (int)r2 < gc + e) { res = x; have = true; }
            }
        }
        unsigned long long hb = __ballot(have);
        int hl = (int)__ffsll((unsigned long long)hb) - 1;
        res = __shfl(res, hl, 64);
        if (lane == 0) {
            float thr = cls_thresh[c];
            float nt = 0.9f * thr + 0.1f * res;
            if (nt >= 1.0f) nt = 0.999f;
            newth[c] = nt;
        }
    }
}

// ---------------- N4: masked reduction + last-block output ----------------
__global__ __launch_bounds__(256)
void k4_reduce_out(const float4* __restrict__ conf, const float4* __restrict__ loss,
                   const uchar4* __restrict__ label, const float* __restrict__ newth,
                   float* __restrict__ accum, unsigned int* __restrict__ done,
                   float* __restrict__ out)
{
    __shared__ float th[NCLS];
    if (threadIdx.x < NCLS) th[threadIdx.x] = newth[threadIdx.x];
    __syncthreads();

    int g = blockIdx.x * 256 + threadIdx.x;
    float4 c4 = conf[g];
    float4 s4 = loss[g];
    uchar4 l4 = label[g];
    float cf[4] = {c4.x, c4.y, c4.z, c4.w};
    float lv[4] = {s4.x, s4.y, s4.z, s4.w};
    int   lb[4] = {l4.x, l4.y, l4.z, l4.w};

    float ls = 0.0f; int mask = 0, solid = 0;
#pragma unroll
    for (int i = 0; i < 4; ++i) {
        bool m = cf[i] > th[lb[i]];
        mask  += m ? 1 : 0;
        solid += (cf[i] > 0.8f) ? 1 : 0;
        ls    += m ? fmaxf(lv[i], 1e-8f) : 0.0f;
    }
    for (int off = 32; off > 0; off >>= 1) {
        ls    += __shfl_down(ls, off, 64);
        mask  += __shfl_down(mask, off, 64);
        solid += __shfl_down(solid, off, 64);
    }
    __shared__ float s_ls[4];
    __shared__ int   s_m[4], s_s[4];
    int w = threadIdx.x >> 6;
    if ((threadIdx.x & 63) == 0) { s_ls[w] = ls; s_m[w] = mask; s_s[w] = solid; }
    __syncthreads();
    if (threadIdx.x == 0) {
        float L = s_ls[0] + s_ls[1] + s_ls[2] + s_ls[3];
        int   M = s_m[0] + s_m[1] + s_m[2] + s_m[3];
        int   S = s_s[0] + s_s[1] + s_s[2] + s_s[3];
        atomicAdd(&accum[0], L);
        atomicAdd(&((unsigned int*)accum)[1], (unsigned)M);
        atomicAdd(&((unsigned int*)accum)[2], (unsigned)S);
    }
    __threadfence();
    __shared__ int s_last;
    if (threadIdx.x == 0) s_last = (atomicAdd(&done[2], 1u) == (unsigned)(gridDim.x - 1)) ? 1 : 0;
    __syncthreads();
    if (!s_last) return;
    __threadfence();                                   // acquire
    if (threadIdx.x == 0) {
        float sum = accum[0];
        unsigned cm = ((const unsigned int*)accum)[1];
        unsigned cs = ((const unsigned int*)accum)[2];
        out[0] = sum / fmaxf((float)cm, 1.0f);
        out[1] = (float)cm / (float)TPIX;
        out[2] = (float)cs / (float)TPIX;
    }
}

extern "C" void kernel_launch(void* const* d_in, const int* in_sizes, int n_in,
                              void* d_out, int out_size, void* d_ws, size_t ws_size,
                              hipStream_t stream)
{
    const float* lb  = (const float*)d_in[0];
    const float* la  = (const float*)d_in[1];
    const float* cth = (const float*)d_in[2];
    float* out = (float*)d_out;

    char* ws = (char*)d_ws;
    unsigned short* part     = (unsigned short*)(ws + WS_PART);
    unsigned int*   cand_cnt = (unsigned int*)(ws + WS_CANDC);
    float*          accum    = (float*)(ws + WS_ACCUM);
    unsigned int*   done     = (unsigned int*)(ws + WS_DONE);
    int*            sel      = (int*)(ws + WS_SEL);
    float*          newth    = (float*)(ws + WS_NEWTH);
    float*          conf     = (float*)(ws + WS_CONF);
    float*          loss     = (float*)(ws + WS_LOSS);
    unsigned char*  label    = (unsigned char*)(ws + WS_LABEL);
    float*          cand     = (float*)(ws + WS_CAND);

    dim3 blk(256);
    dim3 grd1(TPIX / TILE);              // 4096 blocks, 256-px tiles
    dim3 grd4(TPIX / 4 / 256);           // 1024 blocks, 4 px/thread

    k1_pixel<<<grd1, blk, 0, stream>>>(lb, la, conf, loss, label,
                                       cand_cnt, (unsigned int*)accum, done);
    k2_hist_select<<<NPART, blk, 0, stream>>>((const float4*)conf, (const uchar4*)label,
                                              part, cth, sel, cand_cnt, cand, done);
    k3_gather_thresh<<<grd4, blk, 0, stream>>>((const float4*)conf, (const uchar4*)label,
                                               sel, cand_cnt, cand, cth, newth, done);
    k4_reduce_out<<<grd4, blk, 0, stream>>>((const float4*)conf, (const float4*)loss,
                                            (const uchar4*)label, newth, accum, done, out);
}

// Round 3
// 247.822 us; speedup vs baseline: 2.0266x; 2.0266x over previous
//
#include <hip/hip_runtime.h>
#include <math.h>

#define NCLS 19
#define HW   (512*1024)          // 524288
#define CHW  (NCLS*HW)
#define TPIX (2*HW)              // 1048576
#define NB   512                 // coarse bins
#define NPART 32                 // partial histogram copies (u16, fits old slot)
#define CAND_MAX 4096
#define SUBB 1024                // refinement sub-bins per coarse bin
#define SCAP 256                 // refinement candidate cap (per class)

// ---- workspace layout (bytes) ----
// u16 partials: NPART*NCLS*NB*2 = 32*19*512*2 = 622592
#define WS_PART   0
#define WS_CANDC  622592                     // NCLS*4 candidate counters
#define WS_ACCUM  622720                     // [0]=sum_loss f32, [1]=cnt_mask u32, [2]=cnt_solid u32
#define WS_DONE   622784                     // [0]=k5 ticket
#define WS_SEL    622848                     // NCLS * {int bin, int rank}
#define WS_NEWTH  623360                     // NCLS*4
#define WS_CONF   623616                     // TPIX*4
#define WS_LOSS   4817920                    // TPIX*4
#define WS_LABEL  9012224                    // TPIX*1
#define WS_CAND   10060800                   // NCLS*CAND_MAX*4 -> end 10372096

// ---------------- K1: block-cooperative 16B DMA + per-pixel softmax stats ----------------
// (unchanged from R2 — passed correctness; also zeroes the control words)
#define TILE 256
__global__ __launch_bounds__(256)
void k1_pixel(const float* __restrict__ lb_t, const float* __restrict__ la_t,
              float* __restrict__ conf_o, float* __restrict__ loss_o,
              unsigned char* __restrict__ label_o,
              unsigned int* __restrict__ cand_cnt,
              unsigned int* __restrict__ accum_u,
              unsigned int* __restrict__ done)
{
    __shared__ float smem[2 * NCLS * TILE];            // 38912 B -> 4 blocks/CU
    const int tid = threadIdx.x;
    if (blockIdx.x == 0) {                             // zero control area (consumed later)
        if (tid < NCLS)            cand_cnt[tid] = 0u;
        else if (tid < NCLS + 3)   accum_u[tid - NCLS] = 0u;
        else if (tid < NCLS + 6)   done[tid - NCLS - 3] = 0u;
    }
    const int wave = tid >> 6, lane = tid & 63;
    const int tb  = blockIdx.x * TILE;                 // tile never straddles N (HW%256==0)
    const int n   = tb >> 19;
    const int rem = tb & (HW - 1);
    const float* lb = lb_t + (size_t)n * CHW + rem;
    const float* la = la_t + (size_t)n * CHW + rem;

    // 38 channel-rows of 256 px = 1 KB each; wave w stages rows w, w+4, ...
#pragma unroll
    for (int i = 0; i < 10; ++i) {
        int r = wave + 4 * i;
        if (r < 2 * NCLS) {
            const float* src = (r < NCLS) ? (lb + (size_t)r * HW)
                                          : (la + (size_t)(r - NCLS) * HW);
            __builtin_amdgcn_global_load_lds(
                (__attribute__((address_space(1))) void*)(src + (lane << 2)),
                (__attribute__((address_space(3))) void*)(smem + r * TILE),
                16, 0, 0);
        }
    }
    asm volatile("s_waitcnt vmcnt(0)" ::: "memory");
    __syncthreads();

    const int pix = tb + tid;
    float mb, zb, dot, a_lab, ma, za; int lab;
    {
        float bb = smem[tid];
        float aa = smem[NCLS * TILE + tid];
        mb = bb; zb = 1.0f; dot = aa; lab = 0; a_lab = aa; ma = aa; za = 1.0f;
    }
#pragma unroll
    for (int c = 1; c < NCLS; ++c) {
        float b = smem[c * TILE + tid];
        float a = smem[(NCLS + c) * TILE + tid];
        float mn = fmaxf(mb, b);
        float eo = __expf(mb - mn);
        float en = __expf(b - mn);
        zb  = zb * eo + en;
        dot = dot * eo + en * a;
        bool upd = b > mb;                  // first-max-wins (strict >)
        lab   = upd ? c : lab;
        a_lab = upd ? a : a_lab;
        mb = mn;
        float mna = fmaxf(ma, a);
        za = za * __expf(ma - mna) + __expf(a - mna);
        ma = mna;
    }

    float cf = 1.0f / zb;
    float pa_lab = __expf(a_lab - ma) / za;
    float ls = (1.0f - pa_lab) * (ma + __logf(za) - dot / zb);

    conf_o[pix]  = cf;
    loss_o[pix]  = ls;
    label_o[pix] = (unsigned char)lab;
}

// ---------------- K2h: LDS-private partial histograms (parallel, no ticket) ----------------
__global__ __launch_bounds__(512)
void k2_hist(const float4* __restrict__ conf, const uchar4* __restrict__ label,
             unsigned short* __restrict__ part)
{
    __shared__ unsigned int lh[NCLS * NB];             // 38912 B
    const int t = threadIdx.x;
    for (int w = t; w < NCLS * NB; w += 512) lh[w] = 0u;
    __syncthreads();

    const int per4  = TPIX / 4 / NPART;                // 8192 float4 per block
    const int base4 = blockIdx.x * per4;
    for (int i = 0; i < per4 / 512; ++i) {             // 16 iterations
        int g = base4 + i * 512 + t;
        float4 c4 = conf[g];
        uchar4 l4 = label[g];
        float cf[4] = {c4.x, c4.y, c4.z, c4.w};
        int   lb[4] = {l4.x, l4.y, l4.z, l4.w};
#pragma unroll
        for (int k = 0; k < 4; ++k) {
            int bin = (int)(cf[k] * (float)NB);
            bin = bin < (NB - 1) ? bin : (NB - 1);
            atomicAdd(&lh[lb[k] * NB + bin], 1u);      // LDS atomic only
        }
    }
    __syncthreads();

    unsigned short* dst = part + blockIdx.x * (NCLS * NB);
    for (int w = t; w < NCLS * NB; w += 512) dst[w] = (unsigned short)lh[w];  // <=32768 fits u16
}

// ---------------- K2s: reduce partials + per-class rank -> (bin, rank-in-bin) ----------------
// 19 blocks; thread t owns 2 bins; for fixed partial b the u16 reads are
// contiguous across threads (coalesced) -> no single-block latency wall.
__global__ __launch_bounds__(256)
void k2_select(const unsigned short* __restrict__ part, const float* __restrict__ cls_thresh,
               int* __restrict__ sel, unsigned int* __restrict__ cand_cnt,
               float* __restrict__ cand)
{
    int c = blockIdx.x;
    int t = threadIdx.x;
    float thr = cls_thresh[c];
    int thr_bin = (int)(thr * (float)NB); thr_bin = thr_bin < (NB-1) ? thr_bin : (NB-1);

    // thread t owns DESCENDING chunk of 2 bins: [NB-(t+1)*2, NB-t*2)
    int base = NB - (t + 1) * 2;
    unsigned h0 = 0, h1 = 0;
#pragma unroll 8
    for (int b = 0; b < NPART; ++b) {
        const unsigned short* p = part + b * (NCLS * NB) + c * NB;
        h0 += p[base];
        h1 += p[base + 1];
    }
    if (base == thr_bin)     h0 += 1u;                 // extended multiset: append thr
    if (base + 1 == thr_bin) h1 += 1u;
    unsigned s = h0 + h1;

    __shared__ unsigned sc[256];
    sc[t] = s;
    __syncthreads();
    for (int off = 1; off < 256; off <<= 1) {
        unsigned vt = sc[t];
        unsigned vp = (t >= off) ? sc[t - off] : 0u;
        __syncthreads();
        sc[t] = vt + vp;
        __syncthreads();
    }
    unsigned total_ext = sc[255];                      // count_c + 1
    unsigned cnt = total_ext - 1u;
    int idx = (int)floorf((float)(cnt + 1u) * 0.2f * powf(thr, 8.0f));

    unsigned above = sc[t] - s;                        // strictly above this chunk
    if ((unsigned)idx >= above && (unsigned)idx < above + s) {
        int B, r;
        if ((unsigned)idx < above + h1) { B = base + 1; r = (int)((unsigned)idx - above); }
        else                            { B = base;     r = (int)((unsigned)idx - above - h1); }
        sel[2 * c]     = B;
        sel[2 * c + 1] = r;
        if (B == thr_bin) {                            // appended thr is a candidate
            unsigned pos = atomicAdd(&cand_cnt[c], 1u);
            if (pos < CAND_MAX) cand[c * CAND_MAX + pos] = thr;
        }
    }
}

// ---------------- K3: gather candidates in selection bin (4 px/thread) ----------------
__global__ __launch_bounds__(256)
void k3_gather(const float4* __restrict__ conf, const uchar4* __restrict__ label,
               const int* __restrict__ sel, unsigned int* __restrict__ cand_cnt,
               float* __restrict__ cand)
{
    int g = blockIdx.x * 256 + threadIdx.x;
    float4 c4 = conf[g];
    uchar4 l4 = label[g];
    float cf[4] = {c4.x, c4.y, c4.z, c4.w};
    int   lb[4] = {l4.x, l4.y, l4.z, l4.w};
#pragma unroll
    for (int i = 0; i < 4; ++i) {
        int bin = (int)(cf[i] * (float)NB);
        bin = bin < (NB - 1) ? bin : (NB - 1);
        if (bin == sel[2 * lb[i]]) {
            unsigned pos = atomicAdd(&cand_cnt[lb[i]], 1u);
            if (pos < CAND_MAX) cand[lb[i] * CAND_MAX + pos] = cf[i];
        }
    }
}

// ---------------- K4: refined exact rank among candidates -> new_thresh ----------------
// Sub-bin refinement: O(m) histogram + O(k^2) on the tiny selected sub-bin
// (replaces the old O(m^2) ~4M-op loop). Block-wide with barriers.
__global__ __launch_bounds__(256)
void k4_thresh(const int* __restrict__ sel, const unsigned int* __restrict__ cand_cnt,
               const float* __restrict__ cand, const float* __restrict__ cls_thresh,
               float* __restrict__ newth)
{
    __shared__ unsigned int subh[SUBB];                // 4 KB
    __shared__ float        sbuf[SCAP];                // 1 KB
    __shared__ unsigned int scnt;
    __shared__ int          sS;
    __shared__ unsigned int sR2;
    __shared__ float        sres;

    const int c = blockIdx.x;
    const int t = threadIdx.x;
    unsigned mc = cand_cnt[c];
    int m = (int)(mc < (unsigned)CAND_MAX ? mc : (unsigned)CAND_MAX);
    int B = sel[2 * c];
    int r = sel[2 * c + 1];
    const float* v = cand + c * CAND_MAX;
    const float scale = (float)NB;

    for (int i = t; i < SUBB; i += 256) subh[i] = 0u;
    if (t == 0) { scnt = 0u; sS = 0; sR2 = 0u; sres = 0.0f; }
    __syncthreads();

    for (int i = t; i < m; i += 256) {
        float x = v[i];
        int s = (int)((x * scale - (float)B) * (float)SUBB);
        s = s < 0 ? 0 : (s > SUBB - 1 ? SUBB - 1 : s);
        atomicAdd(&subh[s], 1u);
    }
    __syncthreads();

    if (t < 64) {                                      // wave 0: descending scan of sub-bins
        int lane = t;
        int cb = SUBB - 16 * (lane + 1);
        unsigned hsum = 0;
        for (int i = 0; i < 16; ++i) hsum += subh[cb + i];
        unsigned incl = hsum;
        for (int off = 1; off < 64; off <<= 1) {
            unsigned q = __shfl_up(incl, off, 64);
            if (lane >= off) incl += q;
        }
        unsigned above = incl - hsum;
        if ((unsigned)r >= above && (unsigned)r < above + hsum) {
            unsigned cum = above;
            for (int i = 15; i >= 0; --i) {
                unsigned h = subh[cb + i];
                if ((unsigned)r < cum + h) { sS = cb + i; sR2 = (unsigned)r - cum; break; }
                cum += h;
            }
        }
    }
    __syncthreads();
    const int S = sS;
    const unsigned r2 = sR2;

    for (int i = t; i < m; i += 256) {                 // gather sub-bin members
        float x = v[i];
        int s = (int)((x * scale - (float)B) * (float)SUBB);
        s = s < 0 ? 0 : (s > SUBB - 1 ? SUBB - 1 : s);
        if (s == S) {
            unsigned p = atomicAdd(&scnt, 1u);
            if (p < (unsigned)SCAP) sbuf[p] = x;
        }
    }
    __syncthreads();
    unsigned cntS = scnt;

    if (cntS <= (unsigned)SCAP) {
        for (int i = t; i < (int)cntS; i += 256) {
            float x = sbuf[i];
            int gc = 0, e = 0;
            for (int j = 0; j < (int)cntS; ++j) {
                float y = sbuf[j];
                gc += (y > x); e += (y == x);
            }
            if (gc <= (int)r2 && (int)r2 < gc + e) sres = x;   // dups write same value
        }
    } else {
        // safety fallback (dead in practice): exact rank restricted to sub-bin S
        for (int i = t; i < m; i += 256) {
            float x = v[i];
            int s = (int)((x * scale - (float)B) * (float)SUBB);
            s = s < 0 ? 0 : (s > SUBB - 1 ? SUBB - 1 : s);
            if (s != S) continue;
            int gc = 0, e = 0;
            for (int j = 0; j < m; ++j) {
                float y = v[j];
                int sj = (int)((y * scale - (float)B) * (float)SUBB);
                sj = sj < 0 ? 0 : (sj > SUBB - 1 ? SUBB - 1 : sj);
                if (sj != S) continue;
                gc += (y > x); e += (y == x);
            }
            if (gc <= (int)r2 && (int)r2 < gc + e) sres = x;
        }
    }
    __syncthreads();
    if (t == 0) {
        float thr = cls_thresh[c];
        float nt = 0.9f * thr + 0.1f * sres;
        if (nt >= 1.0f) nt = 0.999f;
        newth[c] = nt;
    }
}

// ---------------- K5: masked reduction + last-block output (12-byte serial phase) ----------------
__global__ __launch_bounds__(256)
void k5_reduce_out(const float4* __restrict__ conf, const float4* __restrict__ loss,
                   const uchar4* __restrict__ label, const float* __restrict__ newth,
                   float* __restrict__ accum, unsigned int* __restrict__ done,
                   float* __restrict__ out)
{
    __shared__ float th[NCLS];
    if (threadIdx.x < NCLS) th[threadIdx.x] = newth[threadIdx.x];
    __syncthreads();

    int g = blockIdx.x * 256 + threadIdx.x;
    float4 c4 = conf[g];
    float4 s4 = loss[g];
    uchar4 l4 = label[g];
    float cf[4] = {c4.x, c4.y, c4.z, c4.w};
    float lv[4] = {s4.x, s4.y, s4.z, s4.w};
    int   lb[4] = {l4.x, l4.y, l4.z, l4.w};

    float ls = 0.0f; int mask = 0, solid = 0;
#pragma unroll
    for (int i = 0; i < 4; ++i) {
        bool m = cf[i] > th[lb[i]];
        mask  += m ? 1 : 0;
        solid += (cf[i] > 0.8f) ? 1 : 0;
        ls    += m ? fmaxf(lv[i], 1e-8f) : 0.0f;
    }
    for (int off = 32; off > 0; off >>= 1) {
        ls    += __shfl_down(ls, off, 64);
        mask  += __shfl_down(mask, off, 64);
        solid += __shfl_down(solid, off, 64);
    }
    __shared__ float s_ls[4];
    __shared__ int   s_m[4], s_s[4];
    int w = threadIdx.x >> 6;
    if ((threadIdx.x & 63) == 0) { s_ls[w] = ls; s_m[w] = mask; s_s[w] = solid; }
    __syncthreads();
    __shared__ int s_last;
    if (threadIdx.x == 0) {
        float L = s_ls[0] + s_ls[1] + s_ls[2] + s_ls[3];
        int   M = s_m[0] + s_m[1] + s_m[2] + s_m[3];
        int   S = s_s[0] + s_s[1] + s_s[2] + s_s[3];
        atomicAdd(&accum[0], L);
        atomicAdd(&((unsigned int*)accum)[1], (unsigned)M);
        atomicAdd(&((unsigned int*)accum)[2], (unsigned)S);
        __threadfence();                               // release
        s_last = (atomicAdd(&done[0], 1u) == (unsigned)(gridDim.x - 1)) ? 1 : 0;
    }
    __syncthreads();
    if (!s_last) return;
    if (threadIdx.x == 0) {
        __threadfence();                               // acquire (reads 12 bytes only)
        float sum = accum[0];
        unsigned cm = ((const unsigned int*)accum)[1];
        unsigned cs = ((const unsigned int*)accum)[2];
        out[0] = sum / fmaxf((float)cm, 1.0f);
        out[1] = (float)cm / (float)TPIX;
        out[2] = (float)cs / (float)TPIX;
    }
}

extern "C" void kernel_launch(void* const* d_in, const int* in_sizes, int n_in,
                              void* d_out, int out_size, void* d_ws, size_t ws_size,
                              hipStream_t stream)
{
    const float* lb  = (const float*)d_in[0];
    const float* la  = (const float*)d_in[1];
    const float* cth = (const float*)d_in[2];
    float* out = (float*)d_out;

    char* ws = (char*)d_ws;
    unsigned short* part     = (unsigned short*)(ws + WS_PART);
    unsigned int*   cand_cnt = (unsigned int*)(ws + WS_CANDC);
    float*          accum    = (float*)(ws + WS_ACCUM);
    unsigned int*   done     = (unsigned int*)(ws + WS_DONE);
    int*            sel      = (int*)(ws + WS_SEL);
    float*          newth    = (float*)(ws + WS_NEWTH);
    float*          conf     = (float*)(ws + WS_CONF);
    float*          loss     = (float*)(ws + WS_LOSS);
    unsigned char*  label    = (unsigned char*)(ws + WS_LABEL);
    float*          cand     = (float*)(ws + WS_CAND);

    dim3 grd1(TPIX / TILE);              // 4096 blocks, 256-px tiles
    dim3 grd4(TPIX / 4 / 256);           // 1024 blocks, 4 px/thread

    k1_pixel<<<grd1, dim3(256), 0, stream>>>(lb, la, conf, loss, label,
                                             cand_cnt, (unsigned int*)accum, done);
    k2_hist<<<NPART, dim3(512), 0, stream>>>((const float4*)conf, (const uchar4*)label, part);
    k2_select<<<NCLS, dim3(256), 0, stream>>>(part, cth, sel, cand_cnt, cand);
    k3_gather<<<grd4, dim3(256), 0, stream>>>((const float4*)conf, (const uchar4*)label,
                                              sel, cand_cnt, cand);
    k4_thresh<<<NCLS, dim3(256), 0, stream>>>(sel, cand_cnt, cand, cth, newth);
    k5_reduce_out<<<grd4, dim3(256), 0, stream>>>((const float4*)conf, (const float4*)loss,
                                                  (const uchar4*)label, newth, accum, done, out);
}